// Round 9
// baseline (250.034 us; speedup 1.0000x reference)
//
#include <hip/hip_runtime.h>
#include <stdint.h>

// Problem constants
#define S_LEN   2048
#define D_MODEL 1024
#define N_HEADS 16
#define HEAD_D  64
#define BATCH   2
#define M_TOT   (BATCH * S_LEN)   // 4096 rows for the QKV projection GEMM

typedef __attribute__((ext_vector_type(8))) short s8v;            // 8 x bf16 (MFMA A/B frag)
typedef __attribute__((ext_vector_type(4))) float f4v;            // 4 x f32  (MFMA C/D frag)
typedef __attribute__((ext_vector_type(4))) unsigned short u4v;   // 4 x bf16 packed

__device__ __forceinline__ float bf2f(unsigned short u) {
    union { unsigned int i; float f; } c; c.i = ((unsigned int)u) << 16; return c.f;
}
__device__ __forceinline__ unsigned short f2bf(float f) {
    union { float f; unsigned int i; } c; c.f = f;
    unsigned int u = c.i + 0x7FFFu + ((c.i >> 16) & 1u);   // round-nearest-even
    return (unsigned short)(u >> 16);
}
__device__ __forceinline__ unsigned int pk2bf(float lo, float hi) {
    return (unsigned int)f2bf(lo) | ((unsigned int)f2bf(hi) << 16);
}
// exp2 via the HW transcendental (v_exp_f32)
__device__ __forceinline__ float hw_exp2(float x) { return __builtin_amdgcn_exp2f(x); }

// async global->LDS, 16B per lane; LDS dest is wave-uniform base (+lane*16 implicit)
#define GLD16(gp, lp) __builtin_amdgcn_global_load_lds(                      \
    (const __attribute__((address_space(1))) void*)(const void*)(gp),        \
    (__attribute__((address_space(3))) void*)(void*)(lp), 16, 0, 0)

// barrier WITHOUT draining vmcnt (prefetches stay in flight) but WITH lgkmcnt
// drain: no wave may signal the barrier while its ds_reads of the buffer that
// the next iteration's DMA will overwrite are still outstanding (R5 race fix).
#define BAR_LGKM() asm volatile("s_waitcnt lgkmcnt(0)\n\ts_barrier" ::: "memory")

// exp(x*0.125) == exp2(x * 0.125*log2(e))
#define EXP_SCALE 0.1803368801111204f

// ---------------- kernel 0: fp32 -> bf16 conversion ----------------
__global__ __launch_bounds__(256) void cvt_bf16(const float* __restrict__ src,
                                                unsigned short* __restrict__ dst, int n) {
    int i = (blockIdx.x * 256 + threadIdx.x) * 4;
    int stride = gridDim.x * 1024;
    for (; i < n; i += stride) {
        float4 v = *(const float4*)(src + i);
        u4v o;
        o[0] = f2bf(v.x); o[1] = f2bf(v.y); o[2] = f2bf(v.z); o[3] = f2bf(v.w);
        *(u4v*)(dst + i) = o;
    }
}

// ---------------- kernel 1: QKV projection GEMM (m97 structure) ----------------
__global__ __launch_bounds__(256) void qkv_gemm(
    const unsigned short* __restrict__ X,
    const unsigned short* __restrict__ Wq, const unsigned short* __restrict__ Wk,
    const unsigned short* __restrict__ Wv,
    const float* __restrict__ bq, const float* __restrict__ bk, const float* __restrict__ bv,
    unsigned short* __restrict__ q_ws, unsigned short* __restrict__ k_ws,
    unsigned short* __restrict__ vt_ws) {
    __shared__ unsigned short sA[128 * 32];
    __shared__ unsigned short sB[128 * 32];

    const int z = blockIdx.z;
    const unsigned short* Wm = (z == 0) ? Wq : ((z == 1) ? Wk : Wv);
    const float* bm = (z == 0) ? bq : ((z == 1) ? bk : bv);
    const int m0 = blockIdx.x * 128, n0 = blockIdx.y * 128;
    const int t = threadIdx.x;
    const int lane = t & 63, w = t >> 6;
    const int fr = lane & 15, g = lane >> 4;
    const int wr = w >> 1, wc = w & 1;

    f4v acc[4][4];
#pragma unroll
    for (int i = 0; i < 4; ++i)
#pragma unroll
        for (int j = 0; j < 4; ++j) acc[i][j] = (f4v){0.f, 0.f, 0.f, 0.f};

    const int rowL = t >> 2;
    const int colL = (t & 3) * 8;
    const unsigned short* gA = X + (size_t)(m0 + rowL) * D_MODEL + colL;
    const unsigned short* gB = Wm + (size_t)(n0 + rowL) * D_MODEL + colL;

    for (int kb = 0; kb < 32; ++kb) {
        const int k0 = kb * 32;
        GLD16(gA + k0,                 sA + w * 512);
        GLD16(gA + 64 * D_MODEL + k0,  sA + 2048 + w * 512);
        GLD16(gB + k0,                 sB + w * 512);
        GLD16(gB + 64 * D_MODEL + k0,  sB + 2048 + w * 512);
        __syncthreads();

        s8v af[4], bfv[4];
#pragma unroll
        for (int i = 0; i < 4; ++i)
            af[i] = *(const s8v*)(sA + (wr * 64 + i * 16 + fr) * 32 + g * 8);
#pragma unroll
        for (int j = 0; j < 4; ++j)
            bfv[j] = *(const s8v*)(sB + (wc * 64 + j * 16 + fr) * 32 + g * 8);
#pragma unroll
        for (int i = 0; i < 4; ++i)
#pragma unroll
            for (int j = 0; j < 4; ++j)
                acc[i][j] = __builtin_amdgcn_mfma_f32_16x16x32_bf16(af[i], bfv[j], acc[i][j], 0, 0, 0);
        __syncthreads();
    }

    const int e_base = n0 + wc * 64;
    const int m_base = m0 + wr * 64;
    if (z < 2) {
        unsigned short* dst = (z == 0) ? q_ws : k_ws;
#pragma unroll
        for (int i = 0; i < 4; ++i) {
#pragma unroll
            for (int j = 0; j < 4; ++j) {
                const int e = e_base + j * 16 + fr;
                const int h = e >> 6, dh = e & 63;
                const float bias = bm[e];
                const int mr = m_base + i * 16 + g * 4;
                const int b_ = mr >> 11, srow = mr & 2047;
                const size_t base = (((size_t)(b_ * N_HEADS + h) * S_LEN + srow) << 6) + dh;
#pragma unroll
                for (int r = 0; r < 4; ++r)
                    dst[base + ((size_t)r << 6)] = f2bf(acc[i][j][r] + bias);
            }
        }
    } else {
#pragma unroll
        for (int i = 0; i < 4; ++i) {
#pragma unroll
            for (int j = 0; j < 4; ++j) {
                const int e = e_base + j * 16 + fr;
                const int h = e >> 6, dh = e & 63;
                const float bias = bm[e];
                const int mr = m_base + i * 16 + g * 4;
                const int b_ = mr >> 11, srow = mr & 2047;
                u4v pk;
#pragma unroll
                for (int r = 0; r < 4; ++r) pk[r] = f2bf(acc[i][j][r] + bias);
                *(u4v*)(vt_ws + ((size_t)(b_ * N_HEADS + h) * HEAD_D + dh) * S_LEN + srow) = pk;
            }
        }
    }
}

// ---------------- kernel 2: fused attention, LDS-staged K/V ----------------
// WG (4 waves) = 64 q-rows of one (b,h); wave w owns q-rows [w*16,+16) x ALL keys.
// R9 = R8 with the PL allocation bug fixed: PL needs 16 rows x 128B = 2KB/WAVE
// (R8 gave 1KB -> cross-wave clobber + OOB write past the shared array).
// LDS map (40KB total, 4 WG/CU = 160KB exactly):
//   pass A: KA[buf] = SM + buf*16384          (2 x 16KB, 128-key chunks)
//   pass B: KL[buf] = SM + buf*8192           (2 x 8KB, 64-key chunks)
//           VL[buf] = SM + 16384 + buf*8192   (2 x 8KB)
//   PL (per wave)  = SM + 32768 + w*2048      (4 x 2KB, pass B only)
// Weight stores go directly from MFMA registers (f4v = 4 consecutive keys of one
// q-row) as NT stores, overlapping PV. Sync: per-wave counted vmcnt (never 0
// mid-loop) + raw s_barrier with lgkmcnt(0) drain at end of iteration.
__global__ __launch_bounds__(256, 4) void attn_fused5(
    const unsigned short* __restrict__ q_ws, const unsigned short* __restrict__ k_ws,
    const unsigned short* __restrict__ vt_ws,
    float* __restrict__ out, float* __restrict__ wts) {
    __shared__ __align__(16) char SM[40960];

    const int t = threadIdx.x, lane = t & 63, w = t >> 6;
    const int fr = lane & 15, g = lane >> 4;
    const int blk = blockIdx.x;
    // bits [2:0]=xcd, [7:3]=qt, [9:8]=bh-within-xcd  ->  bijective, XCD-chunked
    const int bh = (blk & 7) * 4 + (blk >> 8);
    const int qt = (blk >> 3) & 31;

    const unsigned short* Qp = q_ws + ((size_t)bh * S_LEN + qt * 64 + w * 16) * HEAD_D;
    const unsigned short* Kp = k_ws + (size_t)bh * S_LEN * HEAD_D;
    const unsigned short* Vt = vt_ws + (size_t)bh * HEAD_D * S_LEN;

    // Q B-frag for swapped QK^T: lane(fr,g) = Q[q=fr][dh g*8..+7], [+32]
    const s8v qa0 = *(const s8v*)(Qp + fr * HEAD_D + g * 8);
    const s8v qa1 = *(const s8v*)(Qp + fr * HEAD_D + 32 + g * 8);

    // 64-key staging (pass B): thread t covers dest bytes t*16 + j*4096; dest
    // 16B-block cb holds global block cb^(row&7) (pre-swizzled source, linear dest)
    auto stageK64 = [&](int c, char* dst) {
#pragma unroll
        for (int j = 0; j < 2; ++j) {
            const int d = t * 16 + j * 4096;
            const int row = d >> 7, cb = (d >> 4) & 7;
            GLD16(Kp + (size_t)(c * 64 + row) * HEAD_D + ((cb ^ (row & 7)) << 3),
                  dst + w * 1024 + j * 4096);
        }
    };
    auto stageV64 = [&](int c, char* dst) {
#pragma unroll
        for (int j = 0; j < 2; ++j) {
            const int d = t * 16 + j * 4096;
            const int row = d >> 7, cb = (d >> 4) & 7;
            GLD16(Vt + (size_t)row * S_LEN + c * 64 + ((cb ^ (row & 7)) << 3),
                  dst + w * 1024 + j * 4096);
        }
    };
    // 128-key staging (pass A): 4 GLD16/thread into a 16KB buffer
    auto stageK128 = [&](int c, char* dst) {
#pragma unroll
        for (int j = 0; j < 4; ++j) {
            const int d = t * 16 + j * 4096;
            const int row = d >> 7, cb = (d >> 4) & 7;
            GLD16(Kp + (size_t)(c * 128 + row) * HEAD_D + ((cb ^ (row & 7)) << 3),
                  dst + w * 1024 + j * 4096);
        }
    };
    // swapped QK^T for one 16-key subtile: lane(fr,g) reg r = S[key st*16+g*4+r][q=fr]
    auto qk16 = [&](const char* kb, int st) -> f4v {
        const int row = st * 16 + fr, m = row & 7;
        const s8v ka0 = *(const s8v*)(kb + row * 128 + ((g ^ m) << 4));
        const s8v ka1 = *(const s8v*)(kb + row * 128 + (((4 + g) ^ m) << 4));
        f4v s = (f4v){0.f, 0.f, 0.f, 0.f};
        s = __builtin_amdgcn_mfma_f32_16x16x32_bf16(ka0, qa0, s, 0, 0, 0);
        s = __builtin_amdgcn_mfma_f32_16x16x32_bf16(ka1, qa1, s, 0, 0, 0);
        return s;
    };

    // ---- pass A: rowsums over 128-key chunks (16 iters, dbuf, counted vmcnt) ----
    float rsum = 0.f;
    stageK128(0, SM);
    for (int c = 0; c < 16; ++c) {
        const int cur = c & 1;
        if (c < 15) stageK128(c + 1, SM + (cur ^ 1) * 16384);
        if (c < 15) asm volatile("s_waitcnt vmcnt(4)" ::: "memory");
        else        asm volatile("s_waitcnt vmcnt(0)" ::: "memory");
        asm volatile("s_barrier" ::: "memory");
        const char* kb = SM + cur * 16384;
#pragma unroll
        for (int st = 0; st < 8; ++st) {
            const f4v s = qk16(kb, st);
#pragma unroll
            for (int r = 0; r < 4; ++r) rsum += hw_exp2(s[r] * EXP_SCALE);
        }
        BAR_LGKM();   // all waves' reads of KA[cur] done before next DMA overwrite
    }
    rsum += __shfl_xor(rsum, 16);
    rsum += __shfl_xor(rsum, 32);
    const float inv = 1.f / rsum;            // per-lane: inv rowsum of q-row fr

    // ---- pass B: recompute scores, direct-reg NT weight stores, PV ----
    f4v acc[4];
#pragma unroll
    for (int i = 0; i < 4; ++i) acc[i] = (f4v){0.f, 0.f, 0.f, 0.f};
    unsigned short* PL = (unsigned short*)(SM + 32768 + w * 2048);  // 2KB/wave
    const int swp = (fr & 7) << 4;
    float* wbase = wts + ((size_t)bh * S_LEN + qt * 64 + w * 16) * S_LEN;

    stageK64(0, SM); stageV64(0, SM + 16384);
    for (int c = 0; c < 32; ++c) {
        const int cur = c & 1;
        if (c < 31) { stageK64(c + 1, SM + (cur ^ 1) * 8192);
                      stageV64(c + 1, SM + 16384 + (cur ^ 1) * 8192); }
        // per-thread VM queue at this wait (oldest first): [c's loads (4)],
        // [c-1's NT stores (4)], [c+1's loads (4)] -> vmcnt(8) drains c's loads.
        if (c == 0)      asm volatile("s_waitcnt vmcnt(4)" ::: "memory");
        else if (c < 31) asm volatile("s_waitcnt vmcnt(8)" ::: "memory");
        else             asm volatile("s_waitcnt vmcnt(4)" ::: "memory");
        asm volatile("s_barrier" ::: "memory");

        const char* kb = SM + cur * 8192;
#pragma unroll
        for (int st = 0; st < 4; ++st) {
            const f4v s = qk16(kb, st);
            f4v p;
#pragma unroll
            for (int r = 0; r < 4; ++r) p[r] = hw_exp2(s[r] * EXP_SCALE) * inv;
            // direct NT store: W[q=fr][c*64 + st*16 + g*4 .. +3] (f32, streamed)
            __builtin_nontemporal_store(p,
                (f4v*)(wbase + (size_t)fr * S_LEN + c * 64 + st * 16 + g * 4));
            // exchange bf16 P into PL for the PV transpose
            const int base = fr * 128 + st * 32 + g * 8;
            *(unsigned int*)((char*)PL + ((base)     ^ swp)) = pk2bf(p[0], p[1]);
            *(unsigned int*)((char*)PL + ((base + 4) ^ swp)) = pk2bf(p[2], p[3]);
        }

        // PV: acc[tt] += P[16q x 32k] @ V[32k x 16dh]
        const char* vl = SM + 16384 + cur * 8192;
#pragma unroll
        for (int ks = 0; ks < 2; ++ks) {
            const s8v pa = *(const s8v*)((const char*)PL +
                                         ((fr * 128 + ks * 64 + g * 16) ^ swp));
#pragma unroll
            for (int tt = 0; tt < 4; ++tt) {
                const int vrow = tt * 16 + fr;
                const s8v vv = *(const s8v*)(vl + vrow * 128 +
                                             (((ks * 4 + g) ^ (vrow & 7)) << 4));
                acc[tt] = __builtin_amdgcn_mfma_f32_16x16x32_bf16(pa, vv, acc[tt], 0, 0, 0);
            }
        }
        BAR_LGKM();   // all waves' reads of KL/VL[cur] done before next DMA overwrite
    }

    // ---- epilogue: O (already normalized), nontemporal ----
    const int b_ = bh >> 4, h = bh & 15;
#pragma unroll
    for (int tt = 0; tt < 4; ++tt)
#pragma unroll
        for (int r = 0; r < 4; ++r)
            __builtin_nontemporal_store(acc[tt][r],
                &out[((size_t)b_ * S_LEN + qt * 64 + w * 16 + g * 4 + r) * D_MODEL +
                     h * HEAD_D + tt * 16 + fr]);
}

// ---------------- launch ----------------
extern "C" void kernel_launch(void* const* d_in, const int* in_sizes, int n_in,
                              void* d_out, int out_size, void* d_ws, size_t ws_size,
                              hipStream_t stream) {
    const float* x  = (const float*)d_in[0];
    const float* Wq = (const float*)d_in[1];
    const float* bq = (const float*)d_in[2];
    const float* Wk = (const float*)d_in[3];
    const float* bk = (const float*)d_in[4];
    const float* Wv = (const float*)d_in[5];
    const float* bv = (const float*)d_in[6];

    float* out = (float*)d_out;                              // [2,2048,1024]
    float* wts = out + (size_t)BATCH * S_LEN * D_MODEL;      // [2,16,2048,2048]

    unsigned short* xb    = (unsigned short*)d_ws;
    unsigned short* wqb   = xb  + (size_t)M_TOT * D_MODEL;
    unsigned short* wkb   = wqb + (size_t)D_MODEL * D_MODEL;
    unsigned short* wvb   = wkb + (size_t)D_MODEL * D_MODEL;
    unsigned short* q_ws  = wvb + (size_t)D_MODEL * D_MODEL;             // [b,h,s,dh]
    unsigned short* k_ws  = q_ws + (size_t)M_TOT * D_MODEL;              // [b,h,s,dh]
    unsigned short* vt_ws = k_ws + (size_t)M_TOT * D_MODEL;              // [b,h,dh,s]

    cvt_bf16<<<1024, 256, 0, stream>>>(x,  xb,  M_TOT * D_MODEL);
    cvt_bf16<<<256,  256, 0, stream>>>(Wq, wqb, D_MODEL * D_MODEL);
    cvt_bf16<<<256,  256, 0, stream>>>(Wk, wkb, D_MODEL * D_MODEL);
    cvt_bf16<<<256,  256, 0, stream>>>(Wv, wvb, D_MODEL * D_MODEL);

    qkv_gemm<<<dim3(32, 8, 3), 256, 0, stream>>>(xb, wqb, wkb, wvb, bq, bk, bv,
                                                 q_ws, k_ws, vt_ws);

    attn_fused5<<<BATCH * N_HEADS * (S_LEN / 64), 256, 0, stream>>>(q_ws, k_ws, vt_ws, out, wts);
}

// Round 10
// 197.859 us; speedup vs baseline: 1.2637x; 1.2637x over previous
//
#include <hip/hip_runtime.h>
#include <stdint.h>

// Problem constants
#define S_LEN   2048
#define D_MODEL 1024
#define N_HEADS 16
#define HEAD_D  64
#define BATCH   2
#define M_TOT   (BATCH * S_LEN)   // 4096 rows for the QKV projection GEMM

typedef __attribute__((ext_vector_type(8))) short s8v;            // 8 x bf16 (MFMA A/B frag)
typedef __attribute__((ext_vector_type(4))) float f4v;            // 4 x f32  (MFMA C/D frag)
typedef __attribute__((ext_vector_type(4))) unsigned short u4v;   // 4 x bf16 packed

__device__ __forceinline__ float bf2f(unsigned short u) {
    union { unsigned int i; float f; } c; c.i = ((unsigned int)u) << 16; return c.f;
}
__device__ __forceinline__ unsigned short f2bf(float f) {
    union { float f; unsigned int i; } c; c.f = f;
    unsigned int u = c.i + 0x7FFFu + ((c.i >> 16) & 1u);   // round-nearest-even
    return (unsigned short)(u >> 16);
}
__device__ __forceinline__ unsigned int pk2bf(float lo, float hi) {
    return (unsigned int)f2bf(lo) | ((unsigned int)f2bf(hi) << 16);
}
// exp2 via the HW transcendental (v_exp_f32)
__device__ __forceinline__ float hw_exp2(float x) { return __builtin_amdgcn_exp2f(x); }

// async global->LDS, 16B per lane; LDS dest is wave-uniform base (+lane*16 implicit)
#define GLD16(gp, lp) __builtin_amdgcn_global_load_lds(                      \
    (const __attribute__((address_space(1))) void*)(const void*)(gp),        \
    (__attribute__((address_space(3))) void*)(void*)(lp), 16, 0, 0)

// barrier WITHOUT draining vmcnt (prefetches stay in flight) but WITH lgkmcnt
// drain: no wave may signal the barrier while its ds_reads of the buffer that
// the next iteration's DMA will overwrite are still outstanding (R5 race fix).
#define BAR_LGKM() asm volatile("s_waitcnt lgkmcnt(0)\n\ts_barrier" ::: "memory")

// exp(x*0.125) == exp2(x * 0.125*log2(e))
#define EXP_SCALE 0.1803368801111204f

// ---------------- kernel 0: fp32 -> bf16 conversion ----------------
__global__ __launch_bounds__(256) void cvt_bf16(const float* __restrict__ src,
                                                unsigned short* __restrict__ dst, int n) {
    int i = (blockIdx.x * 256 + threadIdx.x) * 4;
    int stride = gridDim.x * 1024;
    for (; i < n; i += stride) {
        float4 v = *(const float4*)(src + i);
        u4v o;
        o[0] = f2bf(v.x); o[1] = f2bf(v.y); o[2] = f2bf(v.z); o[3] = f2bf(v.w);
        *(u4v*)(dst + i) = o;
    }
}

// ---------------- kernel 1: QKV projection GEMM (m97 structure) ----------------
__global__ __launch_bounds__(256) void qkv_gemm(
    const unsigned short* __restrict__ X,
    const unsigned short* __restrict__ Wq, const unsigned short* __restrict__ Wk,
    const unsigned short* __restrict__ Wv,
    const float* __restrict__ bq, const float* __restrict__ bk, const float* __restrict__ bv,
    unsigned short* __restrict__ q_ws, unsigned short* __restrict__ k_ws,
    unsigned short* __restrict__ vt_ws) {
    __shared__ unsigned short sA[128 * 32];
    __shared__ unsigned short sB[128 * 32];

    const int z = blockIdx.z;
    const unsigned short* Wm = (z == 0) ? Wq : ((z == 1) ? Wk : Wv);
    const float* bm = (z == 0) ? bq : ((z == 1) ? bk : bv);
    const int m0 = blockIdx.x * 128, n0 = blockIdx.y * 128;
    const int t = threadIdx.x;
    const int lane = t & 63, w = t >> 6;
    const int fr = lane & 15, g = lane >> 4;
    const int wr = w >> 1, wc = w & 1;

    f4v acc[4][4];
#pragma unroll
    for (int i = 0; i < 4; ++i)
#pragma unroll
        for (int j = 0; j < 4; ++j) acc[i][j] = (f4v){0.f, 0.f, 0.f, 0.f};

    const int rowL = t >> 2;
    const int colL = (t & 3) * 8;
    const unsigned short* gA = X + (size_t)(m0 + rowL) * D_MODEL + colL;
    const unsigned short* gB = Wm + (size_t)(n0 + rowL) * D_MODEL + colL;

    for (int kb = 0; kb < 32; ++kb) {
        const int k0 = kb * 32;
        GLD16(gA + k0,                 sA + w * 512);
        GLD16(gA + 64 * D_MODEL + k0,  sA + 2048 + w * 512);
        GLD16(gB + k0,                 sB + w * 512);
        GLD16(gB + 64 * D_MODEL + k0,  sB + 2048 + w * 512);
        __syncthreads();

        s8v af[4], bfv[4];
#pragma unroll
        for (int i = 0; i < 4; ++i)
            af[i] = *(const s8v*)(sA + (wr * 64 + i * 16 + fr) * 32 + g * 8);
#pragma unroll
        for (int j = 0; j < 4; ++j)
            bfv[j] = *(const s8v*)(sB + (wc * 64 + j * 16 + fr) * 32 + g * 8);
#pragma unroll
        for (int i = 0; i < 4; ++i)
#pragma unroll
            for (int j = 0; j < 4; ++j)
                acc[i][j] = __builtin_amdgcn_mfma_f32_16x16x32_bf16(af[i], bfv[j], acc[i][j], 0, 0, 0);
        __syncthreads();
    }

    const int e_base = n0 + wc * 64;
    const int m_base = m0 + wr * 64;
    if (z < 2) {
        unsigned short* dst = (z == 0) ? q_ws : k_ws;
#pragma unroll
        for (int i = 0; i < 4; ++i) {
#pragma unroll
            for (int j = 0; j < 4; ++j) {
                const int e = e_base + j * 16 + fr;
                const int h = e >> 6, dh = e & 63;
                const float bias = bm[e];
                const int mr = m_base + i * 16 + g * 4;
                const int b_ = mr >> 11, srow = mr & 2047;
                const size_t base = (((size_t)(b_ * N_HEADS + h) * S_LEN + srow) << 6) + dh;
#pragma unroll
                for (int r = 0; r < 4; ++r)
                    dst[base + ((size_t)r << 6)] = f2bf(acc[i][j][r] + bias);
            }
        }
    } else {
#pragma unroll
        for (int i = 0; i < 4; ++i) {
#pragma unroll
            for (int j = 0; j < 4; ++j) {
                const int e = e_base + j * 16 + fr;
                const int h = e >> 6, dh = e & 63;
                const float bias = bm[e];
                const int mr = m_base + i * 16 + g * 4;
                const int b_ = mr >> 11, srow = mr & 2047;
                u4v pk;
#pragma unroll
                for (int r = 0; r < 4; ++r) pk[r] = f2bf(acc[i][j][r] + bias);
                *(u4v*)(vt_ws + ((size_t)(b_ * N_HEADS + h) * HEAD_D + dh) * S_LEN + srow) = pk;
            }
        }
    }
}

// ---------------- kernel 2: fused attention, LDS-staged K/V ----------------
// WG (4 waves) = 64 q-rows of one (b,h); wave w owns q-rows [w*16,+16) x ALL keys.
// R10 = R9 with the weight-store path REVERTED to R7's cooperative scheme:
// direct-from-register f4v stores hit 16 rows x 64B segments per instruction
// (4x the transactions on the dominant 540MB stream — the R9 regression);
// cooperative stores from PL give 4 rows x 256B contiguous per instruction.
// Kept from R9: pass-A 128-key chunks (half the barriers), 40KB union LDS map:
//   pass A: KA[buf] = SM + buf*16384          (2 x 16KB)
//   pass B: KL[buf] = SM + buf*8192 ; VL[buf] = SM + 16384 + buf*8192
//   PL (per wave)  = SM + 32768 + w*2048      (16 rows x 128B)
// Sync: per-wave counted vmcnt (never 0 mid-loop) + s_barrier with lgkmcnt(0)
// drain at end of iteration (R6-proven).
__global__ __launch_bounds__(256, 4) void attn_fused6(
    const unsigned short* __restrict__ q_ws, const unsigned short* __restrict__ k_ws,
    const unsigned short* __restrict__ vt_ws,
    float* __restrict__ out, float* __restrict__ wts) {
    __shared__ __align__(16) char SM[40960];

    const int t = threadIdx.x, lane = t & 63, w = t >> 6;
    const int fr = lane & 15, g = lane >> 4;
    const int blk = blockIdx.x;
    // bits [2:0]=xcd, [7:3]=qt, [9:8]=bh-within-xcd  ->  bijective, XCD-chunked
    const int bh = (blk & 7) * 4 + (blk >> 8);
    const int qt = (blk >> 3) & 31;

    const unsigned short* Qp = q_ws + ((size_t)bh * S_LEN + qt * 64 + w * 16) * HEAD_D;
    const unsigned short* Kp = k_ws + (size_t)bh * S_LEN * HEAD_D;
    const unsigned short* Vt = vt_ws + (size_t)bh * HEAD_D * S_LEN;

    // Q B-frag for swapped QK^T: lane(fr,g) = Q[q=fr][dh g*8..+7], [+32]
    const s8v qa0 = *(const s8v*)(Qp + fr * HEAD_D + g * 8);
    const s8v qa1 = *(const s8v*)(Qp + fr * HEAD_D + 32 + g * 8);

    // 64-key staging (pass B): thread t covers dest bytes t*16 + j*4096; dest
    // 16B-block cb holds global block cb^(row&7) (pre-swizzled source, linear dest)
    auto stageK64 = [&](int c, char* dst) {
#pragma unroll
        for (int j = 0; j < 2; ++j) {
            const int d = t * 16 + j * 4096;
            const int row = d >> 7, cb = (d >> 4) & 7;
            GLD16(Kp + (size_t)(c * 64 + row) * HEAD_D + ((cb ^ (row & 7)) << 3),
                  dst + w * 1024 + j * 4096);
        }
    };
    auto stageV64 = [&](int c, char* dst) {
#pragma unroll
        for (int j = 0; j < 2; ++j) {
            const int d = t * 16 + j * 4096;
            const int row = d >> 7, cb = (d >> 4) & 7;
            GLD16(Vt + (size_t)row * S_LEN + c * 64 + ((cb ^ (row & 7)) << 3),
                  dst + w * 1024 + j * 4096);
        }
    };
    // 128-key staging (pass A): 4 GLD16/thread into a 16KB buffer
    auto stageK128 = [&](int c, char* dst) {
#pragma unroll
        for (int j = 0; j < 4; ++j) {
            const int d = t * 16 + j * 4096;
            const int row = d >> 7, cb = (d >> 4) & 7;
            GLD16(Kp + (size_t)(c * 128 + row) * HEAD_D + ((cb ^ (row & 7)) << 3),
                  dst + w * 1024 + j * 4096);
        }
    };
    // swapped QK^T for one 16-key subtile: lane(fr,g) reg r = S[key st*16+g*4+r][q=fr]
    auto qk16 = [&](const char* kb, int st) -> f4v {
        const int row = st * 16 + fr, m = row & 7;
        const s8v ka0 = *(const s8v*)(kb + row * 128 + ((g ^ m) << 4));
        const s8v ka1 = *(const s8v*)(kb + row * 128 + (((4 + g) ^ m) << 4));
        f4v s = (f4v){0.f, 0.f, 0.f, 0.f};
        s = __builtin_amdgcn_mfma_f32_16x16x32_bf16(ka0, qa0, s, 0, 0, 0);
        s = __builtin_amdgcn_mfma_f32_16x16x32_bf16(ka1, qa1, s, 0, 0, 0);
        return s;
    };

    // ---- pass A: rowsums over 128-key chunks (16 iters, dbuf, counted vmcnt) ----
    float rsum = 0.f;
    stageK128(0, SM);
    for (int c = 0; c < 16; ++c) {
        const int cur = c & 1;
        if (c < 15) stageK128(c + 1, SM + (cur ^ 1) * 16384);
        if (c < 15) asm volatile("s_waitcnt vmcnt(4)" ::: "memory");
        else        asm volatile("s_waitcnt vmcnt(0)" ::: "memory");
        asm volatile("s_barrier" ::: "memory");
        const char* kb = SM + cur * 16384;
#pragma unroll
        for (int st = 0; st < 8; ++st) {
            const f4v s = qk16(kb, st);
#pragma unroll
            for (int r = 0; r < 4; ++r) rsum += hw_exp2(s[r] * EXP_SCALE);
        }
        BAR_LGKM();   // all waves' reads of KA[cur] done before next DMA overwrite
    }
    rsum += __shfl_xor(rsum, 16);
    rsum += __shfl_xor(rsum, 32);
    const float inv = 1.f / rsum;            // per-lane: inv rowsum of q-row fr

    // ---- pass B: recompute scores, P->LDS, cooperative NT weight store, PV ----
    f4v acc[4];
#pragma unroll
    for (int i = 0; i < 4; ++i) acc[i] = (f4v){0.f, 0.f, 0.f, 0.f};
    unsigned short* PL = (unsigned short*)(SM + 32768 + w * 2048);  // 2KB/wave
    const int swp = (fr & 7) << 4;
    float* wbase = wts + ((size_t)bh * S_LEN + qt * 64 + w * 16) * S_LEN;

    stageK64(0, SM); stageV64(0, SM + 16384);
    for (int c = 0; c < 32; ++c) {
        const int cur = c & 1;
        if (c < 31) { stageK64(c + 1, SM + (cur ^ 1) * 8192);
                      stageV64(c + 1, SM + 16384 + (cur ^ 1) * 8192); }
        // per-thread VM queue at this wait (oldest first): [c's loads (4)],
        // [c-1's NT stores (4)], [c+1's loads (4)] -> vmcnt(8) drains c's loads.
        if (c == 0)      asm volatile("s_waitcnt vmcnt(4)" ::: "memory");
        else if (c < 31) asm volatile("s_waitcnt vmcnt(8)" ::: "memory");
        else             asm volatile("s_waitcnt vmcnt(4)" ::: "memory");
        asm volatile("s_barrier" ::: "memory");

        const char* kb = SM + cur * 8192;
#pragma unroll
        for (int st = 0; st < 4; ++st) {
            const f4v s = qk16(kb, st);
            f4v p;
#pragma unroll
            for (int r = 0; r < 4; ++r) p[r] = hw_exp2(s[r] * EXP_SCALE) * inv;
            // exchange normalized bf16 P into PL: row q=fr, keys st*16+g*4..+3
            const int base = fr * 128 + st * 32 + g * 8;
            *(unsigned int*)((char*)PL + ((base)     ^ swp)) = pk2bf(p[0], p[1]);
            *(unsigned int*)((char*)PL + ((base + 4) ^ swp)) = pk2bf(p[2], p[3]);
        }

        // cooperative weight store: 4 rows x (16 lanes x 16B = 256B contiguous)
        // per instruction, NONTEMPORAL (streamed, never re-read)
        {
            const int r0 = lane >> 4, cc = lane & 15;
#pragma unroll
            for (int i = 0; i < 4; ++i) {
                const int row = i * 4 + r0;
                const u4v pw = *(const u4v*)((const char*)PL +
                                             ((row * 128 + cc * 8) ^ ((row & 7) << 4)));
                f4v o;
#pragma unroll
                for (int e = 0; e < 4; ++e) o[e] = bf2f(pw[e]);
                __builtin_nontemporal_store(o,
                    (f4v*)(wbase + (size_t)row * S_LEN + c * 64 + cc * 4));
            }
        }

        // PV: acc[tt] += P[16q x 32k] @ V[32k x 16dh]
        const char* vl = SM + 16384 + cur * 8192;
#pragma unroll
        for (int ks = 0; ks < 2; ++ks) {
            const s8v pa = *(const s8v*)((const char*)PL +
                                         ((fr * 128 + ks * 64 + g * 16) ^ swp));
#pragma unroll
            for (int tt = 0; tt < 4; ++tt) {
                const int vrow = tt * 16 + fr;
                const s8v vv = *(const s8v*)(vl + vrow * 128 +
                                             (((ks * 4 + g) ^ (vrow & 7)) << 4));
                acc[tt] = __builtin_amdgcn_mfma_f32_16x16x32_bf16(pa, vv, acc[tt], 0, 0, 0);
            }
        }
        BAR_LGKM();   // all waves' reads of KL/VL[cur] done before next DMA overwrite
    }

    // ---- epilogue: O (already normalized), nontemporal ----
    const int b_ = bh >> 4, h = bh & 15;
#pragma unroll
    for (int tt = 0; tt < 4; ++tt)
#pragma unroll
        for (int r = 0; r < 4; ++r)
            __builtin_nontemporal_store(acc[tt][r],
                &out[((size_t)b_ * S_LEN + qt * 64 + w * 16 + g * 4 + r) * D_MODEL +
                     h * HEAD_D + tt * 16 + fr]);
}

// ---------------- launch ----------------
extern "C" void kernel_launch(void* const* d_in, const int* in_sizes, int n_in,
                              void* d_out, int out_size, void* d_ws, size_t ws_size,
                              hipStream_t stream) {
    const float* x  = (const float*)d_in[0];
    const float* Wq = (const float*)d_in[1];
    const float* bq = (const float*)d_in[2];
    const float* Wk = (const float*)d_in[3];
    const float* bk = (const float*)d_in[4];
    const float* Wv = (const float*)d_in[5];
    const float* bv = (const float*)d_in[6];

    float* out = (float*)d_out;                              // [2,2048,1024]
    float* wts = out + (size_t)BATCH * S_LEN * D_MODEL;      // [2,16,2048,2048]

    unsigned short* xb    = (unsigned short*)d_ws;
    unsigned short* wqb   = xb  + (size_t)M_TOT * D_MODEL;
    unsigned short* wkb   = wqb + (size_t)D_MODEL * D_MODEL;
    unsigned short* wvb   = wkb + (size_t)D_MODEL * D_MODEL;
    unsigned short* q_ws  = wvb + (size_t)D_MODEL * D_MODEL;             // [b,h,s,dh]
    unsigned short* k_ws  = q_ws + (size_t)M_TOT * D_MODEL;              // [b,h,s,dh]
    unsigned short* vt_ws = k_ws + (size_t)M_TOT * D_MODEL;              // [b,h,dh,s]

    cvt_bf16<<<1024, 256, 0, stream>>>(x,  xb,  M_TOT * D_MODEL);
    cvt_bf16<<<256,  256, 0, stream>>>(Wq, wqb, D_MODEL * D_MODEL);
    cvt_bf16<<<256,  256, 0, stream>>>(Wk, wkb, D_MODEL * D_MODEL);
    cvt_bf16<<<256,  256, 0, stream>>>(Wv, wvb, D_MODEL * D_MODEL);

    qkv_gemm<<<dim3(32, 8, 3), 256, 0, stream>>>(xb, wqb, wkb, wvb, bq, bk, bv,
                                                 q_ws, k_ws, vt_ws);

    attn_fused6<<<BATCH * N_HEADS * (S_LEN / 64), 256, 0, stream>>>(q_ws, k_ws, vt_ws, out, wts);
}

// Round 11
// 192.408 us; speedup vs baseline: 1.2995x; 1.0283x over previous
//
#include <hip/hip_runtime.h>
#include <stdint.h>

// Problem constants
#define S_LEN   2048
#define D_MODEL 1024
#define N_HEADS 16
#define HEAD_D  64
#define BATCH   2
#define M_TOT   (BATCH * S_LEN)   // 4096 rows for the QKV projection GEMM

typedef __attribute__((ext_vector_type(8))) short s8v;            // 8 x bf16 (MFMA A/B frag)
typedef __attribute__((ext_vector_type(4))) float f4v;            // 4 x f32  (MFMA C/D frag)
typedef __attribute__((ext_vector_type(4))) unsigned short u4v;   // 4 x bf16 packed

__device__ __forceinline__ float bf2f(unsigned short u) {
    union { unsigned int i; float f; } c; c.i = ((unsigned int)u) << 16; return c.f;
}
__device__ __forceinline__ unsigned short f2bf(float f) {
    union { float f; unsigned int i; } c; c.f = f;
    unsigned int u = c.i + 0x7FFFu + ((c.i >> 16) & 1u);   // round-nearest-even
    return (unsigned short)(u >> 16);
}
__device__ __forceinline__ unsigned int pk2bf(float lo, float hi) {
    return (unsigned int)f2bf(lo) | ((unsigned int)f2bf(hi) << 16);
}
// exp2 via the HW transcendental (v_exp_f32)
__device__ __forceinline__ float hw_exp2(float x) { return __builtin_amdgcn_exp2f(x); }

// async global->LDS, 16B per lane; LDS dest is wave-uniform base (+lane*16 implicit)
#define GLD16(gp, lp) __builtin_amdgcn_global_load_lds(                      \
    (const __attribute__((address_space(1))) void*)(const void*)(gp),        \
    (__attribute__((address_space(3))) void*)(void*)(lp), 16, 0, 0)

// barrier WITHOUT draining vmcnt (prefetches stay in flight) but WITH lgkmcnt
// drain: no wave may signal the barrier while its ds_reads of the buffer that
// the next iteration's DMA will overwrite are still outstanding (R5 race fix).
#define BAR_LGKM() asm volatile("s_waitcnt lgkmcnt(0)\n\ts_barrier" ::: "memory")

// exp(x*0.125) == exp2(x * 0.125*log2(e))
#define EXP_SCALE 0.1803368801111204f

// ---------------- kernel 0: fp32 -> bf16 conversion ----------------
__global__ __launch_bounds__(256) void cvt_bf16(const float* __restrict__ src,
                                                unsigned short* __restrict__ dst, int n) {
    int i = (blockIdx.x * 256 + threadIdx.x) * 4;
    int stride = gridDim.x * 1024;
    for (; i < n; i += stride) {
        float4 v = *(const float4*)(src + i);
        u4v o;
        o[0] = f2bf(v.x); o[1] = f2bf(v.y); o[2] = f2bf(v.z); o[3] = f2bf(v.w);
        *(u4v*)(dst + i) = o;
    }
}

// ---------------- kernel 1: QKV projection GEMM (m97 structure) ----------------
__global__ __launch_bounds__(256) void qkv_gemm(
    const unsigned short* __restrict__ X,
    const unsigned short* __restrict__ Wq, const unsigned short* __restrict__ Wk,
    const unsigned short* __restrict__ Wv,
    const float* __restrict__ bq, const float* __restrict__ bk, const float* __restrict__ bv,
    unsigned short* __restrict__ q_ws, unsigned short* __restrict__ k_ws,
    unsigned short* __restrict__ vt_ws) {
    __shared__ unsigned short sA[128 * 32];
    __shared__ unsigned short sB[128 * 32];

    const int z = blockIdx.z;
    const unsigned short* Wm = (z == 0) ? Wq : ((z == 1) ? Wk : Wv);
    const float* bm = (z == 0) ? bq : ((z == 1) ? bk : bv);
    const int m0 = blockIdx.x * 128, n0 = blockIdx.y * 128;
    const int t = threadIdx.x;
    const int lane = t & 63, w = t >> 6;
    const int fr = lane & 15, g = lane >> 4;
    const int wr = w >> 1, wc = w & 1;

    f4v acc[4][4];
#pragma unroll
    for (int i = 0; i < 4; ++i)
#pragma unroll
        for (int j = 0; j < 4; ++j) acc[i][j] = (f4v){0.f, 0.f, 0.f, 0.f};

    const int rowL = t >> 2;
    const int colL = (t & 3) * 8;
    const unsigned short* gA = X + (size_t)(m0 + rowL) * D_MODEL + colL;
    const unsigned short* gB = Wm + (size_t)(n0 + rowL) * D_MODEL + colL;

    for (int kb = 0; kb < 32; ++kb) {
        const int k0 = kb * 32;
        GLD16(gA + k0,                 sA + w * 512);
        GLD16(gA + 64 * D_MODEL + k0,  sA + 2048 + w * 512);
        GLD16(gB + k0,                 sB + w * 512);
        GLD16(gB + 64 * D_MODEL + k0,  sB + 2048 + w * 512);
        __syncthreads();

        s8v af[4], bfv[4];
#pragma unroll
        for (int i = 0; i < 4; ++i)
            af[i] = *(const s8v*)(sA + (wr * 64 + i * 16 + fr) * 32 + g * 8);
#pragma unroll
        for (int j = 0; j < 4; ++j)
            bfv[j] = *(const s8v*)(sB + (wc * 64 + j * 16 + fr) * 32 + g * 8);
#pragma unroll
        for (int i = 0; i < 4; ++i)
#pragma unroll
            for (int j = 0; j < 4; ++j)
                acc[i][j] = __builtin_amdgcn_mfma_f32_16x16x32_bf16(af[i], bfv[j], acc[i][j], 0, 0, 0);
        __syncthreads();
    }

    const int e_base = n0 + wc * 64;
    const int m_base = m0 + wr * 64;
    if (z < 2) {
        unsigned short* dst = (z == 0) ? q_ws : k_ws;
#pragma unroll
        for (int i = 0; i < 4; ++i) {
#pragma unroll
            for (int j = 0; j < 4; ++j) {
                const int e = e_base + j * 16 + fr;
                const int h = e >> 6, dh = e & 63;
                const float bias = bm[e];
                const int mr = m_base + i * 16 + g * 4;
                const int b_ = mr >> 11, srow = mr & 2047;
                const size_t base = (((size_t)(b_ * N_HEADS + h) * S_LEN + srow) << 6) + dh;
#pragma unroll
                for (int r = 0; r < 4; ++r)
                    dst[base + ((size_t)r << 6)] = f2bf(acc[i][j][r] + bias);
            }
        }
    } else {
#pragma unroll
        for (int i = 0; i < 4; ++i) {
#pragma unroll
            for (int j = 0; j < 4; ++j) {
                const int e = e_base + j * 16 + fr;
                const int h = e >> 6, dh = e & 63;
                const float bias = bm[e];
                const int mr = m_base + i * 16 + g * 4;
                const int b_ = mr >> 11, srow = mr & 2047;
                u4v pk;
#pragma unroll
                for (int r = 0; r < 4; ++r) pk[r] = f2bf(acc[i][j][r] + bias);
                *(u4v*)(vt_ws + ((size_t)(b_ * N_HEADS + h) * HEAD_D + dh) * S_LEN + srow) = pk;
            }
        }
    }
}

// ---------------- kernel 2: fused attention, 2-tile pipelined ----------------
// WG (4 waves) owns TWO 64-row q-tiles of one (b,h); wave w owns rows [w*16,+16)
// of each. Phases:
//   1) pass A(t0): rowsums over K128 chunks (16 iters, no stores)
//   2) pass B(t0) with pass A(t1) INTERLEAVED: each 64-key iteration does
//      QK^T(t0)->weights(t0)+PL+PV(t0) AND QK^T(t1)->rsum1 — the staged K chunk
//      is shared, and t1's MFMA+exp covers the NT store drain. Stores flow.
//   3) pass B(t1). Stores flow.
// Per tile-pair: 80 iters vs 96 unpipelined; store-free window shrinks to the
// 16-iter prologue; K staged 3x instead of 4x.
// Weight stores: cooperative from PL, 4 rows x 256B contiguous per instruction,
// NONTEMPORAL (R10-proven; never scatter the 540MB stream into 64B segments).
// Sync: per-wave counted vmcnt (never 0 mid-loop; in-order retirement makes the
// phase-boundary counts safe) + s_barrier with lgkmcnt(0) drain per iteration.
// LDS 40KB: KA[2x16KB] (phase 1) / KL[2x8KB]+VL[2x8KB] (phases 2-3) + PL 4x2KB.
// Grid = 512 WGs (2/CU). XCD-chunked mapping: 4 heads per XCD (2MB K+V in L2).
__global__ __launch_bounds__(256, 2) void attn_fused7(
    const unsigned short* __restrict__ q_ws, const unsigned short* __restrict__ k_ws,
    const unsigned short* __restrict__ vt_ws,
    float* __restrict__ out, float* __restrict__ wts) {
    __shared__ __align__(16) char SM[40960];

    const int t = threadIdx.x, lane = t & 63, w = t >> 6;
    const int fr = lane & 15, g = lane >> 4;
    const int blk = blockIdx.x;
    // 512 WGs: bits [2:0]=xcd, [6:3]=tile-pair, [8:7]=bh-within-xcd (bijective)
    const int bh = (blk & 7) * 4 + (blk >> 7);
    const int tp = (blk >> 3) & 15;
    const int q0 = tp * 128 + w * 16;        // tile0 rows (this wave)
    const int q1 = q0 + 64;                  // tile1 rows

    const unsigned short* Kp = k_ws + (size_t)bh * S_LEN * HEAD_D;
    const unsigned short* Vt = vt_ws + (size_t)bh * HEAD_D * S_LEN;
    const unsigned short* Qp0 = q_ws + ((size_t)bh * S_LEN + q0) * HEAD_D;
    const unsigned short* Qp1 = q_ws + ((size_t)bh * S_LEN + q1) * HEAD_D;

    // Q B-frags for swapped QK^T: lane(fr,g) = Q[q=fr][dh g*8..+7], [+32]
    const s8v qa00 = *(const s8v*)(Qp0 + fr * HEAD_D + g * 8);
    const s8v qa01 = *(const s8v*)(Qp0 + fr * HEAD_D + 32 + g * 8);
    const s8v qa10 = *(const s8v*)(Qp1 + fr * HEAD_D + g * 8);
    const s8v qa11 = *(const s8v*)(Qp1 + fr * HEAD_D + 32 + g * 8);

    // staging: thread t covers dest bytes t*16 (+j*4096); dest 16B-block cb holds
    // global block cb^(row&7) (pre-swizzled source, linear dest)
    auto stageK64 = [&](int c, char* dst) {
#pragma unroll
        for (int j = 0; j < 2; ++j) {
            const int d = t * 16 + j * 4096;
            const int row = d >> 7, cb = (d >> 4) & 7;
            GLD16(Kp + (size_t)(c * 64 + row) * HEAD_D + ((cb ^ (row & 7)) << 3),
                  dst + w * 1024 + j * 4096);
        }
    };
    auto stageV64 = [&](int c, char* dst) {
#pragma unroll
        for (int j = 0; j < 2; ++j) {
            const int d = t * 16 + j * 4096;
            const int row = d >> 7, cb = (d >> 4) & 7;
            GLD16(Vt + (size_t)row * S_LEN + c * 64 + ((cb ^ (row & 7)) << 3),
                  dst + w * 1024 + j * 4096);
        }
    };
    auto stageK128 = [&](int c, char* dst) {
#pragma unroll
        for (int j = 0; j < 4; ++j) {
            const int d = t * 16 + j * 4096;
            const int row = d >> 7, cb = (d >> 4) & 7;
            GLD16(Kp + (size_t)(c * 128 + row) * HEAD_D + ((cb ^ (row & 7)) << 3),
                  dst + w * 1024 + j * 4096);
        }
    };
    // swapped QK^T, one 16-key subtile: lane(fr,g) reg r = S[key st*16+g*4+r][q=fr]
    auto qk16 = [&](const char* kb, int st, const s8v& a0, const s8v& a1) -> f4v {
        const int row = st * 16 + fr, m = row & 7;
        const s8v ka0 = *(const s8v*)(kb + row * 128 + ((g ^ m) << 4));
        const s8v ka1 = *(const s8v*)(kb + row * 128 + (((4 + g) ^ m) << 4));
        f4v s = (f4v){0.f, 0.f, 0.f, 0.f};
        s = __builtin_amdgcn_mfma_f32_16x16x32_bf16(ka0, a0, s, 0, 0, 0);
        s = __builtin_amdgcn_mfma_f32_16x16x32_bf16(ka1, a1, s, 0, 0, 0);
        return s;
    };

    unsigned short* PL = (unsigned short*)(SM + 32768 + w * 2048);  // 2KB/wave
    const int swp = (fr & 7) << 4;
    const int b_ = bh >> 4, h = bh & 15;

    // ---- phase 1: rowsums(t0) over 128-key chunks ----
    float rsum0 = 0.f;
    stageK128(0, SM);
    for (int c = 0; c < 16; ++c) {
        const int cur = c & 1;
        if (c < 15) stageK128(c + 1, SM + (cur ^ 1) * 16384);
        if (c < 15) asm volatile("s_waitcnt vmcnt(4)" ::: "memory");
        else        asm volatile("s_waitcnt vmcnt(0)" ::: "memory");
        asm volatile("s_barrier" ::: "memory");
        const char* kb = SM + cur * 16384;
#pragma unroll
        for (int st = 0; st < 8; ++st) {
            const f4v s = qk16(kb, st, qa00, qa01);
#pragma unroll
            for (int r = 0; r < 4; ++r) rsum0 += hw_exp2(s[r] * EXP_SCALE);
        }
        BAR_LGKM();
    }
    rsum0 += __shfl_xor(rsum0, 16);
    rsum0 += __shfl_xor(rsum0, 32);
    const float inv0 = 1.f / rsum0;

    // ---- phase 2: pass B(t0) + interleaved rowsums(t1) ----
    f4v acc[4];
#pragma unroll
    for (int i = 0; i < 4; ++i) acc[i] = (f4v){0.f, 0.f, 0.f, 0.f};
    float rsum1 = 0.f;
    float* wbase0 = wts + ((size_t)bh * S_LEN + q0) * S_LEN;

    stageK64(0, SM); stageV64(0, SM + 16384);
    for (int c = 0; c < 32; ++c) {
        const int cur = c & 1;
        if (c < 31) { stageK64(c + 1, SM + (cur ^ 1) * 8192);
                      stageV64(c + 1, SM + 16384 + (cur ^ 1) * 8192); }
        if (c == 0)      asm volatile("s_waitcnt vmcnt(4)" ::: "memory");
        else if (c < 31) asm volatile("s_waitcnt vmcnt(8)" ::: "memory");
        else             asm volatile("s_waitcnt vmcnt(4)" ::: "memory");
        asm volatile("s_barrier" ::: "memory");

        const char* kb = SM + cur * 8192;
        // t0 scores -> normalized bf16 P into PL
#pragma unroll
        for (int st = 0; st < 4; ++st) {
            const f4v s = qk16(kb, st, qa00, qa01);
            f4v p;
#pragma unroll
            for (int r = 0; r < 4; ++r) p[r] = hw_exp2(s[r] * EXP_SCALE) * inv0;
            const int base = fr * 128 + st * 32 + g * 8;
            *(unsigned int*)((char*)PL + ((base)     ^ swp)) = pk2bf(p[0], p[1]);
            *(unsigned int*)((char*)PL + ((base + 4) ^ swp)) = pk2bf(p[2], p[3]);
        }
        // cooperative NT weight store: 4 rows x 256B contiguous per instruction
        {
            const int r0 = lane >> 4, cc = lane & 15;
#pragma unroll
            for (int i = 0; i < 4; ++i) {
                const int row = i * 4 + r0;
                const u4v pw = *(const u4v*)((const char*)PL +
                                             ((row * 128 + cc * 8) ^ ((row & 7) << 4)));
                f4v o;
#pragma unroll
                for (int e = 0; e < 4; ++e) o[e] = bf2f(pw[e]);
                __builtin_nontemporal_store(o,
                    (f4v*)(wbase0 + (size_t)row * S_LEN + c * 64 + cc * 4));
            }
        }
        // t1 rowsums on the SAME staged K (covers the store drain)
#pragma unroll
        for (int st = 0; st < 4; ++st) {
            const f4v s = qk16(kb, st, qa10, qa11);
#pragma unroll
            for (int r = 0; r < 4; ++r) rsum1 += hw_exp2(s[r] * EXP_SCALE);
        }
        // PV(t0)
        const char* vl = SM + 16384 + cur * 8192;
#pragma unroll
        for (int ks = 0; ks < 2; ++ks) {
            const s8v pa = *(const s8v*)((const char*)PL +
                                         ((fr * 128 + ks * 64 + g * 16) ^ swp));
#pragma unroll
            for (int tt = 0; tt < 4; ++tt) {
                const int vrow = tt * 16 + fr;
                const s8v vv = *(const s8v*)(vl + vrow * 128 +
                                             (((ks * 4 + g) ^ (vrow & 7)) << 4));
                acc[tt] = __builtin_amdgcn_mfma_f32_16x16x32_bf16(pa, vv, acc[tt], 0, 0, 0);
            }
        }
        BAR_LGKM();
    }
    rsum1 += __shfl_xor(rsum1, 16);
    rsum1 += __shfl_xor(rsum1, 32);
    const float inv1 = 1.f / rsum1;

    // epilogue t0 (already normalized), nontemporal
#pragma unroll
    for (int tt = 0; tt < 4; ++tt)
#pragma unroll
        for (int r = 0; r < 4; ++r)
            __builtin_nontemporal_store(acc[tt][r],
                &out[((size_t)b_ * S_LEN + q0 + g * 4 + r) * D_MODEL +
                     h * HEAD_D + tt * 16 + fr]);

    // ---- phase 3: pass B(t1) ----
#pragma unroll
    for (int i = 0; i < 4; ++i) acc[i] = (f4v){0.f, 0.f, 0.f, 0.f};
    float* wbase1 = wts + ((size_t)bh * S_LEN + q1) * S_LEN;

    stageK64(0, SM); stageV64(0, SM + 16384);
    for (int c = 0; c < 32; ++c) {
        const int cur = c & 1;
        if (c < 31) { stageK64(c + 1, SM + (cur ^ 1) * 8192);
                      stageV64(c + 1, SM + 16384 + (cur ^ 1) * 8192); }
        if (c == 0)      asm volatile("s_waitcnt vmcnt(4)" ::: "memory");
        else if (c < 31) asm volatile("s_waitcnt vmcnt(8)" ::: "memory");
        else             asm volatile("s_waitcnt vmcnt(4)" ::: "memory");
        asm volatile("s_barrier" ::: "memory");

        const char* kb = SM + cur * 8192;
#pragma unroll
        for (int st = 0; st < 4; ++st) {
            const f4v s = qk16(kb, st, qa10, qa11);
            f4v p;
#pragma unroll
            for (int r = 0; r < 4; ++r) p[r] = hw_exp2(s[r] * EXP_SCALE) * inv1;
            const int base = fr * 128 + st * 32 + g * 8;
            *(unsigned int*)((char*)PL + ((base)     ^ swp)) = pk2bf(p[0], p[1]);
            *(unsigned int*)((char*)PL + ((base + 4) ^ swp)) = pk2bf(p[2], p[3]);
        }
        {
            const int r0 = lane >> 4, cc = lane & 15;
#pragma unroll
            for (int i = 0; i < 4; ++i) {
                const int row = i * 4 + r0;
                const u4v pw = *(const u4v*)((const char*)PL +
                                             ((row * 128 + cc * 8) ^ ((row & 7) << 4)));
                f4v o;
#pragma unroll
                for (int e = 0; e < 4; ++e) o[e] = bf2f(pw[e]);
                __builtin_nontemporal_store(o,
                    (f4v*)(wbase1 + (size_t)row * S_LEN + c * 64 + cc * 4));
            }
        }
        const char* vl = SM + 16384 + cur * 8192;
#pragma unroll
        for (int ks = 0; ks < 2; ++ks) {
            const s8v pa = *(const s8v*)((const char*)PL +
                                         ((fr * 128 + ks * 64 + g * 16) ^ swp));
#pragma unroll
            for (int tt = 0; tt < 4; ++tt) {
                const int vrow = tt * 16 + fr;
                const s8v vv = *(const s8v*)(vl + vrow * 128 +
                                             (((ks * 4 + g) ^ (vrow & 7)) << 4));
                acc[tt] = __builtin_amdgcn_mfma_f32_16x16x32_bf16(pa, vv, acc[tt], 0, 0, 0);
            }
        }
        BAR_LGKM();
    }

    // epilogue t1, nontemporal
#pragma unroll
    for (int tt = 0; tt < 4; ++tt)
#pragma unroll
        for (int r = 0; r < 4; ++r)
            __builtin_nontemporal_store(acc[tt][r],
                &out[((size_t)b_ * S_LEN + q1 + g * 4 + r) * D_MODEL +
                     h * HEAD_D + tt * 16 + fr]);
}

// ---------------- launch ----------------
extern "C" void kernel_launch(void* const* d_in, const int* in_sizes, int n_in,
                              void* d_out, int out_size, void* d_ws, size_t ws_size,
                              hipStream_t stream) {
    const float* x  = (const float*)d_in[0];
    const float* Wq = (const float*)d_in[1];
    const float* bq = (const float*)d_in[2];
    const float* Wk = (const float*)d_in[3];
    const float* bk = (const float*)d_in[4];
    const float* Wv = (const float*)d_in[5];
    const float* bv = (const float*)d_in[6];

    float* out = (float*)d_out;                              // [2,2048,1024]
    float* wts = out + (size_t)BATCH * S_LEN * D_MODEL;      // [2,16,2048,2048]

    unsigned short* xb    = (unsigned short*)d_ws;
    unsigned short* wqb   = xb  + (size_t)M_TOT * D_MODEL;
    unsigned short* wkb   = wqb + (size_t)D_MODEL * D_MODEL;
    unsigned short* wvb   = wkb + (size_t)D_MODEL * D_MODEL;
    unsigned short* q_ws  = wvb + (size_t)D_MODEL * D_MODEL;             // [b,h,s,dh]
    unsigned short* k_ws  = q_ws + (size_t)M_TOT * D_MODEL;              // [b,h,s,dh]
    unsigned short* vt_ws = k_ws + (size_t)M_TOT * D_MODEL;              // [b,h,dh,s]

    cvt_bf16<<<1024, 256, 0, stream>>>(x,  xb,  M_TOT * D_MODEL);
    cvt_bf16<<<256,  256, 0, stream>>>(Wq, wqb, D_MODEL * D_MODEL);
    cvt_bf16<<<256,  256, 0, stream>>>(Wk, wkb, D_MODEL * D_MODEL);
    cvt_bf16<<<256,  256, 0, stream>>>(Wv, wvb, D_MODEL * D_MODEL);

    qkv_gemm<<<dim3(32, 8, 3), 256, 0, stream>>>(xb, wqb, wkb, wvb, bq, bk, bv,
                                                 q_ws, k_ws, vt_ws);

    attn_fused7<<<512, 256, 0, stream>>>(q_ws, k_ws, vt_ws, out, wts);
}

// Round 12
// 185.634 us; speedup vs baseline: 1.3469x; 1.0365x over previous
//
#include <hip/hip_runtime.h>
#include <stdint.h>

// Problem constants
#define S_LEN   2048
#define D_MODEL 1024
#define N_HEADS 16
#define HEAD_D  64
#define BATCH   2
#define M_TOT   (BATCH * S_LEN)   // 4096 rows for the QKV projection GEMM

typedef __attribute__((ext_vector_type(8))) short s8v;            // 8 x bf16 (MFMA A/B frag)
typedef __attribute__((ext_vector_type(4))) float f4v;            // 4 x f32  (MFMA C/D frag)
typedef __attribute__((ext_vector_type(4))) unsigned short u4v;   // 4 x bf16 packed

__device__ __forceinline__ float bf2f(unsigned short u) {
    union { unsigned int i; float f; } c; c.i = ((unsigned int)u) << 16; return c.f;
}
__device__ __forceinline__ unsigned short f2bf(float f) {
    union { float f; unsigned int i; } c; c.f = f;
    unsigned int u = c.i + 0x7FFFu + ((c.i >> 16) & 1u);   // round-nearest-even
    return (unsigned short)(u >> 16);
}
__device__ __forceinline__ unsigned int pk2bf(float lo, float hi) {
    return (unsigned int)f2bf(lo) | ((unsigned int)f2bf(hi) << 16);
}
// exp2 via the HW transcendental (v_exp_f32)
__device__ __forceinline__ float hw_exp2(float x) { return __builtin_amdgcn_exp2f(x); }

// async global->LDS, 16B per lane; LDS dest is wave-uniform base (+lane*16 implicit)
#define GLD16(gp, lp) __builtin_amdgcn_global_load_lds(                      \
    (const __attribute__((address_space(1))) void*)(const void*)(gp),        \
    (__attribute__((address_space(3))) void*)(void*)(lp), 16, 0, 0)

// barrier WITHOUT draining vmcnt (prefetches stay in flight) but WITH lgkmcnt
// drain (R5 race fix: no wave signals the barrier with ds_reads outstanding).
#define BAR_LGKM() asm volatile("s_waitcnt lgkmcnt(0)\n\ts_barrier" ::: "memory")

// exp(x*0.125) == exp2(x * 0.125*log2(e))
#define EXP_SCALE 0.1803368801111204f

// ---------------- kernel 0: fp32 -> bf16 conversion ----------------
__global__ __launch_bounds__(256) void cvt_bf16(const float* __restrict__ src,
                                                unsigned short* __restrict__ dst, int n) {
    int i = (blockIdx.x * 256 + threadIdx.x) * 4;
    int stride = gridDim.x * 1024;
    for (; i < n; i += stride) {
        float4 v = *(const float4*)(src + i);
        u4v o;
        o[0] = f2bf(v.x); o[1] = f2bf(v.y); o[2] = f2bf(v.z); o[3] = f2bf(v.w);
        *(u4v*)(dst + i) = o;
    }
}

// ---------------- kernel 1: QKV projection GEMM (m97 structure) ----------------
__global__ __launch_bounds__(256) void qkv_gemm(
    const unsigned short* __restrict__ X,
    const unsigned short* __restrict__ Wq, const unsigned short* __restrict__ Wk,
    const unsigned short* __restrict__ Wv,
    const float* __restrict__ bq, const float* __restrict__ bk, const float* __restrict__ bv,
    unsigned short* __restrict__ q_ws, unsigned short* __restrict__ k_ws,
    unsigned short* __restrict__ vt_ws) {
    __shared__ unsigned short sA[128 * 32];
    __shared__ unsigned short sB[128 * 32];

    const int z = blockIdx.z;
    const unsigned short* Wm = (z == 0) ? Wq : ((z == 1) ? Wk : Wv);
    const float* bm = (z == 0) ? bq : ((z == 1) ? bk : bv);
    const int m0 = blockIdx.x * 128, n0 = blockIdx.y * 128;
    const int t = threadIdx.x;
    const int lane = t & 63, w = t >> 6;
    const int fr = lane & 15, g = lane >> 4;
    const int wr = w >> 1, wc = w & 1;

    f4v acc[4][4];
#pragma unroll
    for (int i = 0; i < 4; ++i)
#pragma unroll
        for (int j = 0; j < 4; ++j) acc[i][j] = (f4v){0.f, 0.f, 0.f, 0.f};

    const int rowL = t >> 2;
    const int colL = (t & 3) * 8;
    const unsigned short* gA = X + (size_t)(m0 + rowL) * D_MODEL + colL;
    const unsigned short* gB = Wm + (size_t)(n0 + rowL) * D_MODEL + colL;

    for (int kb = 0; kb < 32; ++kb) {
        const int k0 = kb * 32;
        GLD16(gA + k0,                 sA + w * 512);
        GLD16(gA + 64 * D_MODEL + k0,  sA + 2048 + w * 512);
        GLD16(gB + k0,                 sB + w * 512);
        GLD16(gB + 64 * D_MODEL + k0,  sB + 2048 + w * 512);
        __syncthreads();

        s8v af[4], bfv[4];
#pragma unroll
        for (int i = 0; i < 4; ++i)
            af[i] = *(const s8v*)(sA + (wr * 64 + i * 16 + fr) * 32 + g * 8);
#pragma unroll
        for (int j = 0; j < 4; ++j)
            bfv[j] = *(const s8v*)(sB + (wc * 64 + j * 16 + fr) * 32 + g * 8);
#pragma unroll
        for (int i = 0; i < 4; ++i)
#pragma unroll
            for (int j = 0; j < 4; ++j)
                acc[i][j] = __builtin_amdgcn_mfma_f32_16x16x32_bf16(af[i], bfv[j], acc[i][j], 0, 0, 0);
        __syncthreads();
    }

    const int e_base = n0 + wc * 64;
    const int m_base = m0 + wr * 64;
    if (z < 2) {
        unsigned short* dst = (z == 0) ? q_ws : k_ws;
#pragma unroll
        for (int i = 0; i < 4; ++i) {
#pragma unroll
            for (int j = 0; j < 4; ++j) {
                const int e = e_base + j * 16 + fr;
                const int h = e >> 6, dh = e & 63;
                const float bias = bm[e];
                const int mr = m_base + i * 16 + g * 4;
                const int b_ = mr >> 11, srow = mr & 2047;
                const size_t base = (((size_t)(b_ * N_HEADS + h) * S_LEN + srow) << 6) + dh;
#pragma unroll
                for (int r = 0; r < 4; ++r)
                    dst[base + ((size_t)r << 6)] = f2bf(acc[i][j][r] + bias);
            }
        }
    } else {
#pragma unroll
        for (int i = 0; i < 4; ++i) {
#pragma unroll
            for (int j = 0; j < 4; ++j) {
                const int e = e_base + j * 16 + fr;
                const int h = e >> 6, dh = e & 63;
                const float bias = bm[e];
                const int mr = m_base + i * 16 + g * 4;
                const int b_ = mr >> 11, srow = mr & 2047;
                u4v pk;
#pragma unroll
                for (int r = 0; r < 4; ++r) pk[r] = f2bf(acc[i][j][r] + bias);
                *(u4v*)(vt_ws + ((size_t)(b_ * N_HEADS + h) * HEAD_D + dh) * S_LEN + srow) = pk;
            }
        }
    }
}

// ---------------- kernel 2: fused attention, 2-tile pipelined, K128 ----------------
// R12: pass B also uses 128-key chunks -> 48 iterations per tile-pair (was 80),
// each with 2x work against the same per-iteration fixed cost (2 barriers +
// vmcnt/lgkm drains) that R11's counters showed to be the limiter (stores use
// only ~60% of per-CU BW). 8 NT stores x 256B contiguous per lane per iter.
// LDS 80KB (K 2x16 + V 2x16 + PL 4x4KB) -> exactly 2 WG/CU (=160KB), 8 waves/CU
// (R11 proved sufficient). Swizzles: K rows 128B (blk^=row&7, as proven);
// V rows 256B and PL rows 256B use 16-block XOR (blk^=row&15), source-side
// pre-swizzle for the global_load_lds linear dest, matching read-side XOR.
// vmcnt per phase-B iter: prefetch 8 loads + 8 stores -> c==0:8, mid:16, last:8.
__global__ __launch_bounds__(256, 2) void attn_fused8(
    const unsigned short* __restrict__ q_ws, const unsigned short* __restrict__ k_ws,
    const unsigned short* __restrict__ vt_ws,
    float* __restrict__ out, float* __restrict__ wts) {
    __shared__ __align__(16) char SM[81920];
    // K[buf] = SM + buf*16384 ; V[buf] = SM + 32768 + buf*16384 ; PL = SM + 65536 + w*4096

    const int t = threadIdx.x, lane = t & 63, w = t >> 6;
    const int fr = lane & 15, g = lane >> 4;
    const int blk = blockIdx.x;
    // 512 WGs: bits [2:0]=xcd, [6:3]=tile-pair, [8:7]=bh-within-xcd (bijective)
    const int bh = (blk & 7) * 4 + (blk >> 7);
    const int tp = (blk >> 3) & 15;
    const int q0 = tp * 128 + w * 16;        // tile0 rows (this wave)
    const int q1 = q0 + 64;                  // tile1 rows

    const unsigned short* Kp = k_ws + (size_t)bh * S_LEN * HEAD_D;
    const unsigned short* Vt = vt_ws + (size_t)bh * HEAD_D * S_LEN;
    const unsigned short* Qp0 = q_ws + ((size_t)bh * S_LEN + q0) * HEAD_D;
    const unsigned short* Qp1 = q_ws + ((size_t)bh * S_LEN + q1) * HEAD_D;

    const s8v qa00 = *(const s8v*)(Qp0 + fr * HEAD_D + g * 8);
    const s8v qa01 = *(const s8v*)(Qp0 + fr * HEAD_D + 32 + g * 8);
    const s8v qa10 = *(const s8v*)(Qp1 + fr * HEAD_D + g * 8);
    const s8v qa11 = *(const s8v*)(Qp1 + fr * HEAD_D + 32 + g * 8);

    // K128 chunk (16KB): [128 keys][64 dh], 128B rows, blk^=row&7 pre-swizzle
    auto stageK128 = [&](int c, char* dst) {
#pragma unroll
        for (int j = 0; j < 4; ++j) {
            const int d = t * 16 + j * 4096;
            const int row = d >> 7, cb = (d >> 4) & 7;
            GLD16(Kp + (size_t)(c * 128 + row) * HEAD_D + ((cb ^ (row & 7)) << 3),
                  dst + w * 1024 + j * 4096);
        }
    };
    // V128 chunk (16KB): [64 dh][128 keys], 256B rows, blk^=row&15 pre-swizzle
    auto stageV128 = [&](int c, char* dst) {
#pragma unroll
        for (int j = 0; j < 4; ++j) {
            const int d = t * 16 + j * 4096;
            const int row = d >> 8, cb = (d >> 4) & 15;
            GLD16(Vt + (size_t)row * S_LEN + c * 128 + ((cb ^ (row & 15)) << 3),
                  dst + w * 1024 + j * 4096);
        }
    };
    // swapped QK^T, one 16-key subtile: lane(fr,g) reg r = S[key st*16+g*4+r][q=fr]
    auto qk16 = [&](const char* kb, int st, const s8v& a0, const s8v& a1) -> f4v {
        const int row = st * 16 + fr, m = row & 7;
        const s8v ka0 = *(const s8v*)(kb + row * 128 + ((g ^ m) << 4));
        const s8v ka1 = *(const s8v*)(kb + row * 128 + (((4 + g) ^ m) << 4));
        f4v s = (f4v){0.f, 0.f, 0.f, 0.f};
        s = __builtin_amdgcn_mfma_f32_16x16x32_bf16(ka0, a0, s, 0, 0, 0);
        s = __builtin_amdgcn_mfma_f32_16x16x32_bf16(ka1, a1, s, 0, 0, 0);
        return s;
    };

    char* PL = SM + 65536 + w * 4096;        // [16 q][128 keys] bf16, 256B rows
    const int b_ = bh >> 4, h = bh & 15;
    const int r0 = lane >> 4, cc = lane & 15;

    // one pass-B iteration body (st 0..7 over 128 keys)
    auto passB_iter = [&](const char* kb, const char* vl, float inv,
                          const s8v& a0, const s8v& a1, float* wbase, int c,
                          f4v* acc, float* rs_other, const s8v* o0, const s8v* o1) {
        // scores -> normalized bf16 P into PL (swizzled)
#pragma unroll
        for (int st = 0; st < 8; ++st) {
            const f4v s = qk16(kb, st, a0, a1);
            f4v p;
#pragma unroll
            for (int r = 0; r < 4; ++r) p[r] = hw_exp2(s[r] * EXP_SCALE) * inv;
            const int bix = st * 2 + (g >> 1);
            const int wa = fr * 256 + (((bix ^ fr) << 4) | ((g & 1) * 8));
            *(unsigned int*)(PL + wa)     = pk2bf(p[0], p[1]);
            *(unsigned int*)(PL + wa + 4) = pk2bf(p[2], p[3]);
        }
        // cooperative NT weight store: 8 x (16 lanes x 16B = 256B contiguous)
#pragma unroll
        for (int i = 0; i < 4; ++i) {
            const int row = i * 4 + r0;
#pragma unroll
            for (int grp = 0; grp < 2; ++grp) {
                const int bir = grp * 8 + (cc >> 1);
                const u4v pw = *(const u4v*)(PL + row * 256 +
                                             (((bir ^ row) << 4) | ((cc & 1) * 8)));
                f4v o;
#pragma unroll
                for (int e = 0; e < 4; ++e) o[e] = bf2f(pw[e]);
                __builtin_nontemporal_store(o,
                    (f4v*)(wbase + (size_t)row * S_LEN + c * 128 + grp * 64 + cc * 4));
            }
        }
        // other tile's rowsum on the SAME staged K (covers store drain)
        if (rs_other) {
            float acc_rs = 0.f;
#pragma unroll
            for (int st = 0; st < 8; ++st) {
                const f4v s = qk16(kb, st, *o0, *o1);
#pragma unroll
                for (int r = 0; r < 4; ++r) acc_rs += hw_exp2(s[r] * EXP_SCALE);
            }
            *rs_other += acc_rs;
        }
        // PV: acc[tt] += P[16q x 128k] @ V[128k x 16dh]
#pragma unroll
        for (int ks = 0; ks < 4; ++ks) {
            const s8v pa = *(const s8v*)(PL + fr * 256 + (((ks * 4 + g) ^ fr) << 4));
#pragma unroll
            for (int tt = 0; tt < 4; ++tt) {
                const int vrow = tt * 16 + fr;
                const s8v vv = *(const s8v*)(vl + vrow * 256 +
                                             (((ks * 4 + g) ^ (vrow & 15)) << 4));
                acc[tt] = __builtin_amdgcn_mfma_f32_16x16x32_bf16(pa, vv, acc[tt], 0, 0, 0);
            }
        }
    };

    // ---- phase 1: rowsums(t0), K128 chunks ----
    float rsum0 = 0.f;
    stageK128(0, SM);
    for (int c = 0; c < 16; ++c) {
        const int cur = c & 1;
        if (c < 15) stageK128(c + 1, SM + (cur ^ 1) * 16384);
        if (c < 15) asm volatile("s_waitcnt vmcnt(4)" ::: "memory");
        else        asm volatile("s_waitcnt vmcnt(0)" ::: "memory");
        asm volatile("s_barrier" ::: "memory");
        const char* kb = SM + cur * 16384;
#pragma unroll
        for (int st = 0; st < 8; ++st) {
            const f4v s = qk16(kb, st, qa00, qa01);
#pragma unroll
            for (int r = 0; r < 4; ++r) rsum0 += hw_exp2(s[r] * EXP_SCALE);
        }
        BAR_LGKM();
    }
    rsum0 += __shfl_xor(rsum0, 16);
    rsum0 += __shfl_xor(rsum0, 32);
    const float inv0 = 1.f / rsum0;

    // ---- phase 2: pass B(t0) + rowsums(t1), K128+V128 ----
    f4v acc[4];
#pragma unroll
    for (int i = 0; i < 4; ++i) acc[i] = (f4v){0.f, 0.f, 0.f, 0.f};
    float rsum1 = 0.f;
    float* wbase0 = wts + ((size_t)bh * S_LEN + q0) * S_LEN;

    stageK128(0, SM); stageV128(0, SM + 32768);
    for (int c = 0; c < 16; ++c) {
        const int cur = c & 1;
        if (c < 15) { stageK128(c + 1, SM + (cur ^ 1) * 16384);
                      stageV128(c + 1, SM + 32768 + (cur ^ 1) * 16384); }
        if (c == 0)      asm volatile("s_waitcnt vmcnt(8)" ::: "memory");
        else if (c < 15) asm volatile("s_waitcnt vmcnt(16)" ::: "memory");
        else             asm volatile("s_waitcnt vmcnt(8)" ::: "memory");
        asm volatile("s_barrier" ::: "memory");
        passB_iter(SM + cur * 16384, SM + 32768 + cur * 16384, inv0,
                   qa00, qa01, wbase0, c, acc, &rsum1, &qa10, &qa11);
        BAR_LGKM();
    }
    rsum1 += __shfl_xor(rsum1, 16);
    rsum1 += __shfl_xor(rsum1, 32);
    const float inv1 = 1.f / rsum1;

    // epilogue t0 (already normalized), nontemporal
#pragma unroll
    for (int tt = 0; tt < 4; ++tt)
#pragma unroll
        for (int r = 0; r < 4; ++r)
            __builtin_nontemporal_store(acc[tt][r],
                &out[((size_t)b_ * S_LEN + q0 + g * 4 + r) * D_MODEL +
                     h * HEAD_D + tt * 16 + fr]);

    // ---- phase 3: pass B(t1) ----
#pragma unroll
    for (int i = 0; i < 4; ++i) acc[i] = (f4v){0.f, 0.f, 0.f, 0.f};
    float* wbase1 = wts + ((size_t)bh * S_LEN + q1) * S_LEN;

    stageK128(0, SM); stageV128(0, SM + 32768);
    for (int c = 0; c < 16; ++c) {
        const int cur = c & 1;
        if (c < 15) { stageK128(c + 1, SM + (cur ^ 1) * 16384);
                      stageV128(c + 1, SM + 32768 + (cur ^ 1) * 16384); }
        if (c == 0)      asm volatile("s_waitcnt vmcnt(8)" ::: "memory");
        else if (c < 15) asm volatile("s_waitcnt vmcnt(16)" ::: "memory");
        else             asm volatile("s_waitcnt vmcnt(8)" ::: "memory");
        asm volatile("s_barrier" ::: "memory");
        passB_iter(SM + cur * 16384, SM + 32768 + cur * 16384, inv1,
                   qa10, qa11, wbase1, c, acc, nullptr, nullptr, nullptr);
        BAR_LGKM();
    }

    // epilogue t1, nontemporal
#pragma unroll
    for (int tt = 0; tt < 4; ++tt)
#pragma unroll
        for (int r = 0; r < 4; ++r)
            __builtin_nontemporal_store(acc[tt][r],
                &out[((size_t)b_ * S_LEN + q1 + g * 4 + r) * D_MODEL +
                     h * HEAD_D + tt * 16 + fr]);
}

// ---------------- launch ----------------
extern "C" void kernel_launch(void* const* d_in, const int* in_sizes, int n_in,
                              void* d_out, int out_size, void* d_ws, size_t ws_size,
                              hipStream_t stream) {
    const float* x  = (const float*)d_in[0];
    const float* Wq = (const float*)d_in[1];
    const float* bq = (const float*)d_in[2];
    const float* Wk = (const float*)d_in[3];
    const float* bk = (const float*)d_in[4];
    const float* Wv = (const float*)d_in[5];
    const float* bv = (const float*)d_in[6];

    float* out = (float*)d_out;                              // [2,2048,1024]
    float* wts = out + (size_t)BATCH * S_LEN * D_MODEL;      // [2,16,2048,2048]

    unsigned short* xb    = (unsigned short*)d_ws;
    unsigned short* wqb   = xb  + (size_t)M_TOT * D_MODEL;
    unsigned short* wkb   = wqb + (size_t)D_MODEL * D_MODEL;
    unsigned short* wvb   = wkb + (size_t)D_MODEL * D_MODEL;
    unsigned short* q_ws  = wvb + (size_t)D_MODEL * D_MODEL;             // [b,h,s,dh]
    unsigned short* k_ws  = q_ws + (size_t)M_TOT * D_MODEL;              // [b,h,s,dh]
    unsigned short* vt_ws = k_ws + (size_t)M_TOT * D_MODEL;              // [b,h,dh,s]

    cvt_bf16<<<1024, 256, 0, stream>>>(x,  xb,  M_TOT * D_MODEL);
    cvt_bf16<<<256,  256, 0, stream>>>(Wq, wqb, D_MODEL * D_MODEL);
    cvt_bf16<<<256,  256, 0, stream>>>(Wk, wkb, D_MODEL * D_MODEL);
    cvt_bf16<<<256,  256, 0, stream>>>(Wv, wvb, D_MODEL * D_MODEL);

    qkv_gemm<<<dim3(32, 8, 3), 256, 0, stream>>>(xb, wqb, wkb, wvb, bq, bk, bv,
                                                 q_ws, k_ws, vt_ws);

    attn_fused8<<<512, 256, 0, stream>>>(q_ws, k_ws, vt_ws, out, wts);
}